// Round 2
// baseline (442.576 us; speedup 1.0000x reference)
//
#include <hip/hip_runtime.h>
#include <math.h>

#define EPS 1e-6f

typedef float f4 __attribute__((ext_vector_type(4)));

__device__ __forceinline__ float elu1(float x) {
    // elu(x) + 1  ==  x+1 (x>0)  |  exp(x) (x<=0)
    return x > 0.0f ? x + 1.0f : __expf(x);
}

// One block per (b,n). D = M = 256. 256 threads = 4 waves of 64 lanes.
// Wave w owns the contiguous row chunk [64w, 64w+64) of Si.
// Phase 2 is an 8-row register double-buffer: load batch g+1 (8x16B per
// lane in flight), then a clustered burst of 8 {FMA + nontemporal store}
// for batch g. Batching reads vs writes reduces HBM bus turnaround; the
// first batch's loads are issued BEFORE phase 1 so the feature-map +
// reduction phase hides the first HBM latency.
// Grid = 1024 blocks on 256 CUs caps occupancy at 4 blocks/CU, so VGPR
// use up to 128/wave is free — the 16x f4 pipeline costs nothing.
__global__ __launch_bounds__(256) void rla_kernel(
    const float* __restrict__ query,
    const float* __restrict__ key,
    const float* __restrict__ value,
    const float* __restrict__ Si,
    const float* __restrict__ Zi,
    float* __restrict__ V_out,
    float* __restrict__ Si_out,
    float* __restrict__ Zi_out)
{
    const int bn = blockIdx.x;      // 0 .. B*N-1
    const int t  = threadIdx.x;     // 0 .. 255

    __shared__ float sQ[256];
    __shared__ float sK[256];
    __shared__ float red[4 * 256];
    __shared__ float sden[4];
    __shared__ float sZ;

    const size_t base = (size_t)bn * 256;

    const int c = t & 63;            // column group (lane): 4 floats each
    const int w = t >> 6;            // wave id
    const int row0 = w * 64;         // this wave's first Si row

    // row stride in f4 units = 64 (256 floats)
    const f4* SiB = (const f4*)(Si     + (size_t)bn * 65536) + (size_t)row0 * 64 + c;
    f4*       SoB = (f4*)      (Si_out + (size_t)bn * 65536) + (size_t)row0 * 64 + c;

    // ---- Issue first Si batch early: in flight during phase 1 ----
    f4 cur[8], nxt[8];
    #pragma unroll
    for (int j = 0; j < 8; ++j)
        cur[j] = __builtin_nontemporal_load(SiB + j * 64);

    const f4 v = ((const f4*)(value + base))[c];

    // ---- Phase 1: feature maps, Zi_new, denominator reduction ----
    float q  = elu1(query[base + t]);
    float k  = elu1(key[base + t]);
    float zn = Zi[base + t] + k;
    Zi_out[base + t] = zn;
    sQ[t] = q;
    sK[t] = k;

    float part = q * zn;
    #pragma unroll
    for (int off = 32; off > 0; off >>= 1)
        part += __shfl_down(part, off, 64);
    if ((t & 63) == 0) sden[t >> 6] = part;
    __syncthreads();                 // sQ/sK/sden visible
    if (t == 0) {
        float den = sden[0] + sden[1] + sden[2] + sden[3];
        sZ = 1.0f / (den + EPS);
    }

    // ---- Phase 2: Si sweep, 8-row double-buffered register pipeline ----
    const float* Kp = sK + row0;     // wave-uniform LDS broadcasts
    const float* Qp = sQ + row0;

    f4 acc = (f4)(0.0f);

    for (int g = 1; g < 8; ++g) {
        // load batch g (8 independent 16B NT loads)
        #pragma unroll
        for (int j = 0; j < 8; ++j)
            nxt[j] = __builtin_nontemporal_load(SiB + (g * 8 + j) * 64);
        // compute + store batch g-1 (clustered write burst)
        const int rp = (g - 1) * 8;
        #pragma unroll
        for (int j = 0; j < 8; ++j) {
            f4 n = cur[j] + Kp[rp + j] * v;
            __builtin_nontemporal_store(n, SoB + (rp + j) * 64);
            acc += Qp[rp + j] * n;
        }
        #pragma unroll
        for (int j = 0; j < 8; ++j) cur[j] = nxt[j];
    }
    // epilogue: batch 7
    #pragma unroll
    for (int j = 0; j < 8; ++j) {
        f4 n = cur[j] + Kp[56 + j] * v;
        __builtin_nontemporal_store(n, SoB + (56 + j) * 64);
        acc += Qp[56 + j] * n;
    }

    // ---- Combine the 4 waves' partial V, scale by Z ----
    ((f4*)(red + w * 256))[c] = acc;
    __syncthreads();                 // red + sZ visible
    const float vsum = red[0 * 256 + t] + red[1 * 256 + t]
                     + red[2 * 256 + t] + red[3 * 256 + t];
    V_out[base + t] = vsum * sZ;
}

extern "C" void kernel_launch(void* const* d_in, const int* in_sizes, int n_in,
                              void* d_out, int out_size, void* d_ws, size_t ws_size,
                              hipStream_t stream) {
    const float* query = (const float*)d_in[0];
    const float* key_  = (const float*)d_in[1];
    const float* value = (const float*)d_in[2];
    const float* Si    = (const float*)d_in[3];
    const float* Zi    = (const float*)d_in[4];

    const int BN = in_sizes[0] / 256;          // B*N = 1024
    float* V_out  = (float*)d_out;                             // [BN, 256]
    float* Si_out = V_out + (size_t)BN * 256;                  // [BN, 256, 256]
    float* Zi_out = Si_out + (size_t)BN * 256 * 256;           // [BN, 256]

    rla_kernel<<<BN, 256, 0, stream>>>(query, key_, value, Si, Zi,
                                       V_out, Si_out, Zi_out);
}